// Round 2
// baseline (459.628 us; speedup 1.0000x reference)
//
#include <hip/hip_runtime.h>

#define EPSQ 1e-8f

// x: (32, 32, 192, 192) f32; weight: (32, 32, 3, 3) f32; bias: (32,) f32; bits: (32,) i32
// Batch elems = 32*192*192 = 1179648 = 36 * 32768.

// ---------------- Kernel A: per-(batch, chunk) min/max partials ----------------
__global__ __launch_bounds__(256) void kA_partial_minmax(
    const float* __restrict__ x, float* __restrict__ partials)
{
    const int batch = blockIdx.x / 36;
    const int blk   = blockIdx.x % 36;
    const float* xb = x + (size_t)batch * 1179648 + (size_t)blk * 32768;
    float mn = INFINITY, mx = -INFINITY;
#pragma unroll
    for (int i = 0; i < 32; ++i) {
        const float4 v = reinterpret_cast<const float4*>(xb)[i * 256 + threadIdx.x];
        mn = fminf(mn, fminf(fminf(v.x, v.y), fminf(v.z, v.w)));
        mx = fmaxf(mx, fmaxf(fmaxf(v.x, v.y), fmaxf(v.z, v.w)));
    }
    __shared__ float smn[256], smx[256];
    smn[threadIdx.x] = mn; smx[threadIdx.x] = mx;
    __syncthreads();
    for (int s = 128; s > 0; s >>= 1) {
        if (threadIdx.x < s) {
            smn[threadIdx.x] = fminf(smn[threadIdx.x], smn[threadIdx.x + s]);
            smx[threadIdx.x] = fmaxf(smx[threadIdx.x], smx[threadIdx.x + s]);
        }
        __syncthreads();
    }
    if (threadIdx.x == 0) {
        partials[blockIdx.x * 2 + 0] = smn[0];
        partials[blockIdx.x * 2 + 1] = smx[0];
    }
}

// ---------------- Kernel B: group stats + quantized transposed weights ----------------
// gstats[g*2+0] = mn_g, gstats[g*2+1] = scale_g   (g: 0->b=2, 1->b=4, 2->b=8)
// wq_t[g][ (ci*9 + k)*32 + co ] = quantized weight, co-contiguous
__global__ __launch_bounds__(256) void kB_stats_and_wq(
    const float* __restrict__ w, const int* __restrict__ bits,
    const float* __restrict__ partials, float* __restrict__ gstats,
    float* __restrict__ wq_t)
{
    __shared__ float bmn[32], bmx[32];
    __shared__ float red[256];
    __shared__ float s_wmn, s_wmx;
    const int tid = threadIdx.x;

    if (tid < 32) {
        float mn = INFINITY, mx = -INFINITY;
        for (int i = 0; i < 36; ++i) {
            mn = fminf(mn, partials[(tid * 36 + i) * 2 + 0]);
            mx = fmaxf(mx, partials[(tid * 36 + i) * 2 + 1]);
        }
        bmn[tid] = mn; bmx[tid] = mx;
    }

    // weight min/max over 9216 elements
    float wmn = INFINITY, wmx = -INFINITY;
    for (int i = tid; i < 9216; i += 256) {
        const float v = w[i];
        wmn = fminf(wmn, v); wmx = fmaxf(wmx, v);
    }
    red[tid] = wmn; __syncthreads();
    for (int s = 128; s > 0; s >>= 1) { if (tid < s) red[tid] = fminf(red[tid], red[tid + s]); __syncthreads(); }
    if (tid == 0) s_wmn = red[0];
    __syncthreads();
    red[tid] = wmx; __syncthreads();
    for (int s = 128; s > 0; s >>= 1) { if (tid < s) red[tid] = fmaxf(red[tid], red[tid + s]); __syncthreads(); }
    if (tid == 0) s_wmx = red[0];
    __syncthreads();

    // group stats (3 groups)
    if (tid < 3) {
        const int bval = 2 << tid;                       // 2, 4, 8
        const float denom = (float)((1 << bval) - 1);    // 3, 15, 255
        float mn = INFINITY, mx = -INFINITY; bool has = false;
        for (int nb = 0; nb < 32; ++nb) {
            if (bits[nb] == bval) { has = true; mn = fminf(mn, bmn[nb]); mx = fmaxf(mx, bmx[nb]); }
        }
        if (!has) { mn = 0.f; mx = 0.f; }
        const float scale = fmaxf((mx - mn) / denom, EPSQ);
        gstats[tid * 2 + 0] = mn;
        gstats[tid * 2 + 1] = scale;
    }

    // quantize weights for all 3 groups into transposed layout
    const float wmnv = s_wmn, wmxv = s_wmx;
    for (int g = 0; g < 3; ++g) {
        const int bval = 2 << g;
        const float denom = (float)((1 << bval) - 1);
        const float wsc = fmaxf((wmxv - wmnv) / denom, EPSQ);
        for (int i = tid; i < 9216; i += 256) {
            const int co = i / 288;          // original layout [co][ci][kh][kw]
            const int rem = i % 288;         // rem = ci*9 + k
            const float v = w[i];
            const float q = rintf((v - wmnv) / wsc) * wsc + wmnv;
            wq_t[g * 9216 + rem * 32 + co] = q;
        }
    }
}

// ---------------- Kernel C: quantize-on-load conv3x3 ----------------
// grid = (12, 12, 32); block = 256.
// Tile: 16x16 output pixels, all 32 co. Thread: 8 co x 4 px.
__global__ __launch_bounds__(256) void kC_conv(
    const float* __restrict__ x, const float* __restrict__ bias,
    const int* __restrict__ bits, const float* __restrict__ gstats,
    const float* __restrict__ wq_t, float* __restrict__ out)
{
    __shared__ float wlds[9216];            // [ci][k][co], co contiguous (all 32 ci)
    __shared__ float xlds[16][18][20];      // [ci-half][row+halo][col+halo, padded]

    const int n  = blockIdx.z;
    const int oy = blockIdx.y * 16;
    const int ox = blockIdx.x * 16;
    const int tid = threadIdx.x;

    const int bval = bits[n];
    const int g = (bval == 2) ? 0 : (bval == 4 ? 1 : 2);
    const float mn    = gstats[g * 2 + 0];
    const float scale = gstats[g * 2 + 1];

    // stage weights for this group
    const float* wg = wq_t + g * 9216;
    for (int i = tid; i < 9216; i += 256) wlds[i] = wg[i];

    const int co_g = tid >> 6;              // 0..3 -> co base = co_g*8
    const int lane = tid & 63;
    const int row  = lane >> 2;             // 0..15
    const int colb = (lane & 3) * 4;        // 0,4,8,12

    float acc[8][4];
#pragma unroll
    for (int c = 0; c < 8; ++c)
#pragma unroll
        for (int j = 0; j < 4; ++j) acc[c][j] = 0.f;

    const float* xn = x + (size_t)n * 32 * 192 * 192;

    for (int half = 0; half < 2; ++half) {
        __syncthreads();   // wlds ready (half 0); xlds consumers done (half 1)
        // stage + quantize x tile: ci in [half*16, half*16+16), rows/cols with halo
        for (int idx = tid; idx < 16 * 18 * 18; idx += 256) {
            const int c  = idx % 18;
            const int r  = (idx / 18) % 18;
            const int ci = idx / 324;
            const int gy = oy + r - 1, gx = ox + c - 1;
            float v = 0.f;   // conv pads x_q with exact 0
            if (gy >= 0 && gy < 192 && gx >= 0 && gx < 192) {
                v = xn[((size_t)(half * 16 + ci) * 192 + gy) * 192 + gx];
                v = rintf((v - mn) / scale) * scale + mn;   // IEEE div: bit-exact vs ref
            }
            xlds[ci][r][c] = v;
        }
        __syncthreads();

        for (int ci = 0; ci < 16; ++ci) {
            float xr[3][8];
#pragma unroll
            for (int kh = 0; kh < 3; ++kh) {
                *(float4*)&xr[kh][0] = *(const float4*)&xlds[ci][row + kh][colb + 0];
                *(float4*)&xr[kh][4] = *(const float4*)&xlds[ci][row + kh][colb + 4];
            }
#pragma unroll
            for (int kh = 0; kh < 3; ++kh) {
#pragma unroll
                for (int kw = 0; kw < 3; ++kw) {
                    // FIX (r1): weight channel index must include the ci-half offset.
                    const float* wp = &wlds[(((half * 16 + ci) * 9) + kh * 3 + kw) * 32 + co_g * 8];
                    const float4 w0 = *(const float4*)(wp + 0);
                    const float4 w1 = *(const float4*)(wp + 4);
                    const float wv[8] = {w0.x, w0.y, w0.z, w0.w, w1.x, w1.y, w1.z, w1.w};
#pragma unroll
                    for (int c = 0; c < 8; ++c)
#pragma unroll
                        for (int j = 0; j < 4; ++j)
                            acc[c][j] += xr[kh][j + kw] * wv[c];
                }
            }
        }
    }

    // epilogue: bias + store
#pragma unroll
    for (int c = 0; c < 8; ++c) {
        const int co = co_g * 8 + c;
        const float bv = bias[co];
        float4 v;
        v.x = acc[c][0] + bv; v.y = acc[c][1] + bv;
        v.z = acc[c][2] + bv; v.w = acc[c][3] + bv;
        *(float4*)&out[(((size_t)n * 32 + co) * 192 + (oy + row)) * 192 + ox + colb] = v;
    }
}

extern "C" void kernel_launch(void* const* d_in, const int* in_sizes, int n_in,
                              void* d_out, int out_size, void* d_ws, size_t ws_size,
                              hipStream_t stream) {
    const float* x      = (const float*)d_in[0];
    const float* weight = (const float*)d_in[1];
    const float* bias   = (const float*)d_in[2];
    const int*   bits   = (const int*)d_in[3];
    float* out = (float*)d_out;

    float* ws       = (float*)d_ws;
    float* partials = ws;            // 32*36*2 = 2304 floats
    float* gstats   = ws + 2304;     // 8 floats (3 groups x {mn, scale}, padded)
    float* wq_t     = ws + 2312;     // 3*9216 = 27648 floats

    kA_partial_minmax<<<32 * 36, 256, 0, stream>>>(x, partials);
    kB_stats_and_wq<<<1, 256, 0, stream>>>(weight, bits, partials, gstats, wq_t);

    dim3 grid(12, 12, 32);
    kC_conv<<<grid, 256, 0, stream>>>(x, bias, bits, gstats, wq_t, out);
}

// Round 3
// 380.252 us; speedup vs baseline: 1.2087x; 1.2087x over previous
//
#include <hip/hip_runtime.h>

#define EPSQ 1e-8f

// x: (32, 32, 192, 192) f32; weight: (32, 32, 3, 3) f32; bias: (32,) f32; bits: (32,) i32

// ---------------- Kernel A: per-(batch, chunk) min/max partials ----------------
__global__ __launch_bounds__(256) void kA_partial_minmax(
    const float* __restrict__ x, float* __restrict__ partials)
{
    const int batch = blockIdx.x / 36;
    const int blk   = blockIdx.x % 36;
    const float* xb = x + (size_t)batch * 1179648 + (size_t)blk * 32768;
    float mn = INFINITY, mx = -INFINITY;
#pragma unroll
    for (int i = 0; i < 32; ++i) {
        const float4 v = reinterpret_cast<const float4*>(xb)[i * 256 + threadIdx.x];
        mn = fminf(mn, fminf(fminf(v.x, v.y), fminf(v.z, v.w)));
        mx = fmaxf(mx, fmaxf(fmaxf(v.x, v.y), fmaxf(v.z, v.w)));
    }
    __shared__ float smn[256], smx[256];
    smn[threadIdx.x] = mn; smx[threadIdx.x] = mx;
    __syncthreads();
    for (int s = 128; s > 0; s >>= 1) {
        if (threadIdx.x < s) {
            smn[threadIdx.x] = fminf(smn[threadIdx.x], smn[threadIdx.x + s]);
            smx[threadIdx.x] = fmaxf(smx[threadIdx.x], smx[threadIdx.x + s]);
        }
        __syncthreads();
    }
    if (threadIdx.x == 0) {
        partials[blockIdx.x * 2 + 0] = smn[0];
        partials[blockIdx.x * 2 + 1] = smx[0];
    }
}

// ---------------- Kernel B: group stats + quantized transposed weights ----------------
// gstats[g*2+0]=mn_g, gstats[g*2+1]=scale_g  (g: 0->b=2, 1->b=4, 2->b=8)
// wq_t[g][(ci*9 + k)*32 + co], co contiguous
__global__ __launch_bounds__(256) void kB_stats_and_wq(
    const float* __restrict__ w, const int* __restrict__ bits,
    const float* __restrict__ partials, float* __restrict__ gstats,
    float* __restrict__ wq_t)
{
    __shared__ float bmn[32], bmx[32];
    __shared__ float red[256];
    __shared__ float s_wmn, s_wmx;
    const int tid = threadIdx.x;

    if (tid < 32) {
        float mn = INFINITY, mx = -INFINITY;
        for (int i = 0; i < 36; ++i) {
            mn = fminf(mn, partials[(tid * 36 + i) * 2 + 0]);
            mx = fmaxf(mx, partials[(tid * 36 + i) * 2 + 1]);
        }
        bmn[tid] = mn; bmx[tid] = mx;
    }

    float wmn = INFINITY, wmx = -INFINITY;
    for (int i = tid; i < 9216; i += 256) {
        const float v = w[i];
        wmn = fminf(wmn, v); wmx = fmaxf(wmx, v);
    }
    red[tid] = wmn; __syncthreads();
    for (int s = 128; s > 0; s >>= 1) { if (tid < s) red[tid] = fminf(red[tid], red[tid + s]); __syncthreads(); }
    if (tid == 0) s_wmn = red[0];
    __syncthreads();
    red[tid] = wmx; __syncthreads();
    for (int s = 128; s > 0; s >>= 1) { if (tid < s) red[tid] = fmaxf(red[tid], red[tid + s]); __syncthreads(); }
    if (tid == 0) s_wmx = red[0];
    __syncthreads();

    if (tid < 3) {
        const int bval = 2 << tid;
        const float denom = (float)((1 << bval) - 1);
        float mn = INFINITY, mx = -INFINITY; bool has = false;
        for (int nb = 0; nb < 32; ++nb) {
            if (bits[nb] == bval) { has = true; mn = fminf(mn, bmn[nb]); mx = fmaxf(mx, bmx[nb]); }
        }
        if (!has) { mn = 0.f; mx = 0.f; }
        const float scale = fmaxf((mx - mn) / denom, EPSQ);
        gstats[tid * 2 + 0] = mn;
        gstats[tid * 2 + 1] = scale;
    }

    const float wmnv = s_wmn, wmxv = s_wmx;
    for (int g = 0; g < 3; ++g) {
        const int bval = 2 << g;
        const float denom = (float)((1 << bval) - 1);
        const float wsc = fmaxf((wmxv - wmnv) / denom, EPSQ);
        for (int i = tid; i < 9216; i += 256) {
            const int co = i / 288;
            const int rem = i % 288;
            const float v = w[i];
            const float q = rintf((v - wmnv) / wsc) * wsc + wmnv;
            wq_t[g * 9216 + rem * 32 + co] = q;
        }
    }
}

// ---------------- Kernel C: quantize-on-load conv3x3 ----------------
// grid = (6, 12, 32); block = 256 (4 waves).
// Tile: 16 rows x 32 cols x all 32 co. Thread: 8 co x (2 rows x 4 cols).
// ci staged in quarters of 8 -> LDS = 20.25 + 9 = 29.3 KB -> 3 blocks/CU.
// x LDS stride 36 floats: 8-lane phase groups tile all 32 banks (conflict-free b128).
__global__ __launch_bounds__(256, 3) void kC_conv(
    const float* __restrict__ x, const float* __restrict__ bias,
    const int* __restrict__ bits, const float* __restrict__ gstats,
    const float* __restrict__ wq_t, float* __restrict__ out)
{
    __shared__ float xq[8][18][36];   // [ci][row+halo][col+halo, pad 34->36]
    __shared__ float wlq[2304];       // [ci][tap][co] for current quarter

    const int n  = blockIdx.z;
    const int oy = blockIdx.y * 16;
    const int ox = blockIdx.x * 32;
    const int tid = threadIdx.x;

    const int bval = bits[n];
    const int g = (bval == 2) ? 0 : (bval == 4 ? 1 : 2);
    const float mn    = gstats[g * 2 + 0];
    const float scale = gstats[g * 2 + 1];

    const int co_g = tid >> 6;        // 0..3 -> co base = co_g*8
    const int lane = tid & 63;
    const int rp   = lane >> 3;       // 0..7 -> output rows 2rp, 2rp+1
    const int cq   = lane & 7;        // 0..7 -> output cols 4cq..4cq+3

    float acc[8][8];                  // [co][r2*4+j]
#pragma unroll
    for (int c = 0; c < 8; ++c)
#pragma unroll
        for (int j = 0; j < 8; ++j) acc[c][j] = 0.f;

    const float* xn = x + (size_t)n * 32 * 192 * 192;

    for (int q = 0; q < 4; ++q) {
        __syncthreads();              // previous quarter's consumers done
        const int ci0 = q * 8;

        // stage weights (linear copy, 9 iters)
        const float* wsrc = wq_t + g * 9216 + ci0 * 288;
        for (int i = tid; i < 2304; i += 256) wlq[i] = wsrc[i];

        // stage + quantize x quarter: 8 ci x 18 rows x 34 cols
        for (int idx = tid; idx < 4896; idx += 256) {
            const int ci  = idx / 612;             // 18*34
            const int rem = idx - ci * 612;
            const int r   = rem / 34;
            const int c   = rem - r * 34;
            const int gy = oy + r - 1, gx = ox + c - 1;
            float v = 0.f;                          // conv pads x_q with exact 0
            if ((unsigned)gy < 192u && (unsigned)gx < 192u) {
                v = xn[((size_t)(ci0 + ci) * 192 + gy) * 192 + gx];
                v = rintf((v - mn) / scale) * scale + mn;  // IEEE div: matches ref
            }
            xq[ci][r][c] = v;
        }
        __syncthreads();

#pragma unroll 2
        for (int ci = 0; ci < 8; ++ci) {
            float xr[4][8];
#pragma unroll
            for (int dr = 0; dr < 4; ++dr) {
                *(float4*)&xr[dr][0] = *(const float4*)&xq[ci][2 * rp + dr][4 * cq];
                *(float4*)&xr[dr][4] = *(const float4*)&xq[ci][2 * rp + dr][4 * cq + 4];
            }
#pragma unroll
            for (int kh = 0; kh < 3; ++kh) {
#pragma unroll
                for (int kw = 0; kw < 3; ++kw) {
                    const float* wp = &wlq[(ci * 9 + kh * 3 + kw) * 32 + co_g * 8];
                    const float4 w0 = *(const float4*)(wp + 0);
                    const float4 w1 = *(const float4*)(wp + 4);
                    const float wv[8] = {w0.x, w0.y, w0.z, w0.w, w1.x, w1.y, w1.z, w1.w};
#pragma unroll
                    for (int c = 0; c < 8; ++c) {
#pragma unroll
                        for (int r2 = 0; r2 < 2; ++r2) {
#pragma unroll
                            for (int j = 0; j < 4; ++j)
                                acc[c][r2 * 4 + j] += xr[r2 + kh][j + kw] * wv[c];
                        }
                    }
                }
            }
        }
    }

    // epilogue: bias + store (2 float4 per co)
#pragma unroll
    for (int c = 0; c < 8; ++c) {
        const int co = co_g * 8 + c;
        const float bv = bias[co];
#pragma unroll
        for (int r2 = 0; r2 < 2; ++r2) {
            float4 v;
            v.x = acc[c][r2 * 4 + 0] + bv;
            v.y = acc[c][r2 * 4 + 1] + bv;
            v.z = acc[c][r2 * 4 + 2] + bv;
            v.w = acc[c][r2 * 4 + 3] + bv;
            *(float4*)&out[(((size_t)n * 32 + co) * 192 + (oy + 2 * rp + r2)) * 192 + ox + 4 * cq] = v;
        }
    }
}

extern "C" void kernel_launch(void* const* d_in, const int* in_sizes, int n_in,
                              void* d_out, int out_size, void* d_ws, size_t ws_size,
                              hipStream_t stream) {
    const float* x      = (const float*)d_in[0];
    const float* weight = (const float*)d_in[1];
    const float* bias   = (const float*)d_in[2];
    const int*   bits   = (const int*)d_in[3];
    float* out = (float*)d_out;

    float* ws       = (float*)d_ws;
    float* partials = ws;            // 32*36*2 = 2304 floats
    float* gstats   = ws + 2304;     // 8 floats
    float* wq_t     = ws + 2312;     // 3*9216 floats

    kA_partial_minmax<<<32 * 36, 256, 0, stream>>>(x, partials);
    kB_stats_and_wq<<<1, 256, 0, stream>>>(weight, bits, partials, gstats, wq_t);

    dim3 grid(6, 12, 32);
    kC_conv<<<grid, 256, 0, stream>>>(x, bias, bits, gstats, wq_t, out);
}